// Round 11
// baseline (581.889 us; speedup 1.0000x reference)
//
#include <hip/hip_runtime.h>

#define KNB 48

typedef float  floatx4 __attribute__((ext_vector_type(4)));
typedef __bf16 bf16x8  __attribute__((ext_vector_type(8)));
typedef unsigned short ushort8  __attribute__((ext_vector_type(8)));
typedef unsigned short ushort4v __attribute__((ext_vector_type(4)));

__device__ __forceinline__ float bf2f(unsigned short b) {
  union { unsigned int u; float f; } v; v.u = ((unsigned int)b) << 16; return v.f;
}
__device__ __forceinline__ unsigned short f2bf(float f) {
  __bf16 h = (__bf16)f;
  union { __bf16 h; unsigned short u; } v; v.h = h; return v.u;
}
__device__ __forceinline__ bf16x8 pack8(floatx4 a, floatx4 b) {
  bf16x8 r;
  r[0] = (__bf16)a[0]; r[1] = (__bf16)a[1]; r[2] = (__bf16)a[2]; r[3] = (__bf16)a[3];
  r[4] = (__bf16)b[0]; r[5] = (__bf16)b[1]; r[6] = (__bf16)b[2]; r[7] = (__bf16)b[3];
  return r;
}
// GELU via sigmoid-form tanh approximation (max |err| ~3e-4 vs exact).
__device__ __forceinline__ float gelu_f(float x) {
  float u = x * (0.7978845608f + 0.0356774081f * x * x);
  float t = __builtin_amdgcn_exp2f(u * -2.8853900818f);
  return x * __builtin_amdgcn_rcpf(1.0f + t);
}

#define MFMA16(a, b, c) __builtin_amdgcn_mfma_f32_16x16x32_bf16((a), (b), (c), 0, 0, 0)

// ---------------------------------------------------------------------------
// k0: transpose fp32 weights into bf16 [n][k] tables
// ---------------------------------------------------------------------------
__global__ __launch_bounds__(256) void k0_transpose(
    const float* mW1, const float* mW2, const float* mW3,
    const float* fW1, const float* fW2,
    unsigned short* MT1, unsigned short* WT2, unsigned short* WT3,
    unsigned short* FWT1, unsigned short* FWT2) {
  __shared__ unsigned short tile[32][33];
  int b = blockIdx.x;
  const float* src; unsigned short* dst; int Kd, Nd, t;
  if (b < 64)       { src = mW1; dst = MT1;  Kd = 512; Nd = 128; t = b; }
  else if (b < 80)  { src = mW2; dst = WT2;  Kd = 128; Nd = 128; t = b - 64; }
  else if (b < 96)  { src = mW3; dst = WT3;  Kd = 128; Nd = 128; t = b - 80; }
  else if (b < 160) { src = fW1; dst = FWT1; Kd = 128; Nd = 512; t = b - 96; }
  else              { src = fW2; dst = FWT2; Kd = 512; Nd = 128; t = b - 160; }
  int tN = Nd >> 5;
  int tk = t / tN, tn = t % tN;
  int tx = threadIdx.x & 31, ty = threadIdx.x >> 5;  // 32x8
  for (int r = 0; r < 4; ++r) {
    int row = ty + r * 8;
    tile[row][tx] = f2bf(src[(size_t)(tk * 32 + row) * Nd + tn * 32 + tx]);
  }
  __syncthreads();
  for (int r = 0; r < 4; ++r) {
    int row = ty + r * 8;
    dst[(size_t)(tn * 32 + row) * Kd + tk * 32 + tx] = tile[tx][row];
  }
}

// ---------------------------------------------------------------------------
// k1: node precompute tables:
//   Apr[i] = node_h[i] @ mW1[0:128]   + mb1          (fp32)
//   BS[j][0:128]   = node_h[j] @ mW1[128:256]        (bf16)
//   BS[j][128:256] = seq_emb[j] @ mW1[384:512]       (bf16)
// ---------------------------------------------------------------------------
__global__ __launch_bounds__(256) void k1_nodepre(
    const float* node_h, const float* seq_emb,
    const unsigned short* MT1, const float* mb1,
    float* Apr, unsigned short* BS) {
  __shared__ __align__(16) unsigned short sX[2][32 * 128];
  int r0 = blockIdx.x * 32;
  int tid = threadIdx.x, lane = tid & 63, w = tid >> 6;
  int l15 = lane & 15, l16 = lane >> 4;

  for (int mset = 0; mset < 2; ++mset) {
    const float* src = mset ? (seq_emb + (size_t)r0 * 128) : (node_h + (size_t)r0 * 128);
    for (int k = 0; k < 4; ++k) {
      int f = tid + 256 * k;
      floatx4 v = ((const floatx4*)src)[f];
      int row = f >> 5, hc = f & 31, c = hc >> 1, half = hc & 1;
      ushort4v o;
      o[0] = f2bf(v[0]); o[1] = f2bf(v[1]); o[2] = f2bf(v[2]); o[3] = f2bf(v[3]);
      *(ushort4v*)((char*)&sX[mset][0] + row * 256 + ((c ^ (row & 7)) << 4) + half * 8) = o;
    }
  }
  __syncthreads();

  for (int q = 0; q < 6; ++q) {
    int job = w + 4 * q;
    int kind = job >> 3;                 // 0:Apr 1:B 2:S
    int nt = job & 7;
    int colOff = (kind == 0) ? 0 : (kind == 1) ? 128 : 384;
    const unsigned short* X = sX[kind == 2 ? 1 : 0];
    bf16x8 wf[4];
    for (int kk = 0; kk < 4; ++kk)
      wf[kk] = *(const bf16x8*)(MT1 + (size_t)(nt * 16 + l15) * 512 + colOff + kk * 32 + l16 * 8);
    for (int mt = 0; mt < 2; ++mt) {
      floatx4 acc = {0.f, 0.f, 0.f, 0.f};
      for (int kk = 0; kk < 4; ++kk) {
        int row = mt * 16 + l15;
        int off = (kk * 64 + l16 * 16) ^ ((row & 7) << 4);
        bf16x8 a = *(const bf16x8*)((const char*)X + row * 256 + off);
        acc = MFMA16(a, wf[kk], acc);
      }
      int col = nt * 16 + l15;
      for (int r = 0; r < 4; ++r) {
        int row = r0 + mt * 16 + l16 * 4 + r;
        if (kind == 0)      Apr[(size_t)row * 128 + col] = acc[r] + mb1[col];
        else if (kind == 1) BS[(size_t)row * 256 + col] = f2bf(acc[r]);
        else                BS[(size_t)row * 256 + 128 + col] = f2bf(acc[r]);
      }
    }
  }
}

// ---------------------------------------------------------------------------
// k2: edge MLP, transposed orientation: EDGES ON THE MFMA N AXIS.
// 1 wave = 1 node = 3 subtiles of 16 edges. 4 waves/block (256 thr), zero
// barriers, 4 KB wave-private LDS each.
//   A-frag  = weight tables (same addressing as old wf loads)
//   B-frag  = E^T, contiguous 16 B direct from global fp32 (no staging)
//   C-in L1 = gvec^T (Apr + B[j] + m*S[j]) -- no gvec LDS pass
//   C-out   = 4 consecutive FEATURES of one edge -> packed ds_write_b64
//   L3 eliminated: sum_e(t2 @ W3) == (sum_e t2) @ W3; k2 accumulates
//   sum_e t2 in fp32 regs (exact), k3 does the tiny GEMV.
// ---------------------------------------------------------------------------
__global__ __launch_bounds__(256, 4) void k2_edge(
    const float* edge_h, const int* edge_idx, const float* ar_mask,
    const unsigned short* MT1, const unsigned short* WT2,
    const float* mb2,
    const float* Apr, const unsigned short* BS,
    float* sumT2) {
  __shared__ __align__(16) unsigned short sX[4][16 * 128];
  int tid = threadIdx.x, lane = tid & 63, w = tid >> 6;
  int l15 = lane & 15, l16 = lane >> 4;
  int node = blockIdx.x * 4 + w;
  char* X = (char*)&sX[w][0];
  int xsw = (l15 & 7) << 4;

  float vsum[32];                       // [mt][r]: sum over this lane's edges
#pragma unroll
  for (int q = 0; q < 32; ++q) vsum[q] = 0.f;

  for (int sub = 0; sub < 3; ++sub) {
    int e = node * KNB + sub * 16 + l15;
    int jj = edge_idx[e];
    float mk = ar_mask[e];

    // E^T B-frags: contiguous 16B-equivalent from global fp32
    bf16x8 bE[4];
#pragma unroll
    for (int kk = 0; kk < 4; ++kk) {
      const floatx4* ep = (const floatx4*)(edge_h + (size_t)e * 128 + kk * 32 + l16 * 8);
      bE[kk] = pack8(ep[0], ep[1]);
    }

    // ---- layer 1: C-in = gvec^T; C += W1e-frag x E^T-frag; gelu -> X (b64)
#pragma unroll
    for (int mt = 0; mt < 8; ++mt) {
      int f0 = mt * 16 + l16 * 4;
      floatx4 ap = *(const floatx4*)(Apr + (size_t)node * 128 + f0);
      ushort4v vb = *(const ushort4v*)(BS + (size_t)jj * 256 + f0);
      ushort4v vs = *(const ushort4v*)(BS + (size_t)jj * 256 + 128 + f0);
      floatx4 c;
#pragma unroll
      for (int r = 0; r < 4; ++r) c[r] = ap[r] + bf2f(vb[r]) + mk * bf2f(vs[r]);
#pragma unroll
      for (int kk = 0; kk < 4; ++kk) {
        bf16x8 a = *(const bf16x8*)(MT1 + (size_t)(mt * 16 + l15) * 512 + 256 + kk * 32 + l16 * 8);
        c = MFMA16(a, bE[kk], c);
      }
      ushort4v o;
#pragma unroll
      for (int r = 0; r < 4; ++r) o[r] = f2bf(gelu_f(c[r]));
      *(ushort4v*)(X + l15 * 256 + ((mt * 32 + l16 * 8) ^ xsw)) = o;
    }

    // ---- t1 B-frags from own X rows (wave-private, compiler orders)
    bf16x8 bT[4];
#pragma unroll
    for (int kk = 0; kk < 4; ++kk)
      bT[kk] = *(const bf16x8*)(X + l15 * 256 + ((kk * 64 + l16 * 16) ^ xsw));

    // ---- layer 2: C-in = mb2; C += W2-frag x t1^T-frag; gelu -> vsum (fp32)
#pragma unroll
    for (int mt = 0; mt < 8; ++mt) {
      int f0 = mt * 16 + l16 * 4;
      floatx4 c = *(const floatx4*)(mb2 + f0);
#pragma unroll
      for (int kk = 0; kk < 4; ++kk) {
        bf16x8 a = *(const bf16x8*)(WT2 + (size_t)(mt * 16 + l15) * 128 + kk * 32 + l16 * 8);
        c = MFMA16(a, bT[kk], c);
      }
#pragma unroll
      for (int r = 0; r < 4; ++r) vsum[mt * 4 + r] += gelu_f(c[r]);
    }
  }

  // ---- reduce over the 16 edge-lanes (l15) and write sum_t2[node]
#pragma unroll
  for (int q = 0; q < 32; ++q) {
    vsum[q] += __shfl_xor(vsum[q], 1);
    vsum[q] += __shfl_xor(vsum[q], 2);
    vsum[q] += __shfl_xor(vsum[q], 4);
    vsum[q] += __shfl_xor(vsum[q], 8);
  }
  if (l15 == 0) {
#pragma unroll
    for (int mt = 0; mt < 8; ++mt) {
      floatx4 o;
#pragma unroll
      for (int r = 0; r < 4; ++r) o[r] = vsum[mt * 4 + r];
      *(floatx4*)(sumT2 + (size_t)node * 128 + mt * 16 + l16 * 4) = o;
    }
  }
}

// ---------------------------------------------------------------------------
// k3: agg = sumT2 @ W3 + 48*mb3 (tiny GEMV via MFMA), then
//     h=LN(node_h+agg); ff=gelu(h@fW1+fb1)@fW2+fb2; out=LN(h+ff)
// ---------------------------------------------------------------------------
__global__ __launch_bounds__(256) void k3_ff(
    const float* node_h, const float* sumT2,
    const unsigned short* WT3, const float* mb3,
    const unsigned short* FWT1, const unsigned short* FWT2,
    const float* fb1, const float* fb2,
    const float* g1, const float* b1,
    const float* g2, const float* b2,
    float* out) {
  __shared__ __align__(16) unsigned short sS[32 * 128];
  __shared__ float sAgg[32 * 128];
  __shared__ __align__(16) unsigned short sH[32 * 128];
  __shared__ __align__(16) unsigned short sT3[32 * 512];
  __shared__ float sP[32 * 128];
  int r0 = blockIdx.x * 32;
  int tid = threadIdx.x, lane = tid & 63, w = tid >> 6;
  int l15 = lane & 15, l16 = lane >> 4;

  // stage sumT2 -> sS (bf16, swizzled)
  {
    const float* src = sumT2 + (size_t)r0 * 128;
    for (int k = 0; k < 4; ++k) {
      int f = tid + 256 * k;
      floatx4 v = ((const floatx4*)src)[f];
      int row = f >> 5, hc = f & 31, c = hc >> 1, half = hc & 1;
      ushort4v o;
      o[0] = f2bf(v[0]); o[1] = f2bf(v[1]); o[2] = f2bf(v[2]); o[3] = f2bf(v[3]);
      *(ushort4v*)((char*)sS + row * 256 + ((c ^ (row & 7)) << 4) + half * 8) = o;
    }
  }
  __syncthreads();

  // GEMV: sAgg = sS @ WT3 + 48*mb3
  for (int n = 0; n < 2; ++n) {
    int nt = w * 2 + n;
    bf16x8 wf[4];
    for (int kk = 0; kk < 4; ++kk)
      wf[kk] = *(const bf16x8*)(WT3 + (size_t)(nt * 16 + l15) * 128 + kk * 32 + l16 * 8);
    for (int mt = 0; mt < 2; ++mt) {
      floatx4 acc = {0.f,0.f,0.f,0.f};
      for (int kk = 0; kk < 4; ++kk) {
        int row = mt * 16 + l15;
        int off = (kk * 64 + l16 * 16) ^ ((row & 7) << 4);
        bf16x8 a = *(const bf16x8*)((const char*)sS + row * 256 + off);
        acc = MFMA16(a, wf[kk], acc);
      }
      int col = nt * 16 + l15;
      for (int r = 0; r < 4; ++r) {
        int row = mt * 16 + l16 * 4 + r;
        sAgg[row * 128 + col] = acc[r] + 48.0f * mb3[col];
      }
    }
  }
  __syncthreads();

  // load + LN1 (node_h global + sAgg LDS)
  {
    int row = tid >> 3;
    int c0 = (tid & 7) * 16;
    const floatx4* nh4 = (const floatx4*)(node_h + (size_t)(r0 + row) * 128 + c0);
    const floatx4* ag4 = (const floatx4*)(&sAgg[row * 128 + c0]);
    float x[16]; float sum = 0.f, sum2 = 0.f;
#pragma unroll
    for (int q4 = 0; q4 < 4; ++q4) {
      floatx4 a = nh4[q4], g = ag4[q4];
#pragma unroll
      for (int j = 0; j < 4; ++j) {
        float xv = a[j] + g[j];
        x[q4 * 4 + j] = xv; sum += xv; sum2 += xv * xv;
      }
    }
    sum  += __shfl_xor(sum, 1);  sum  += __shfl_xor(sum, 2);  sum  += __shfl_xor(sum, 4);
    sum2 += __shfl_xor(sum2, 1); sum2 += __shfl_xor(sum2, 2); sum2 += __shfl_xor(sum2, 4);
    float mu = sum * (1.f / 128.f);
    float var = sum2 * (1.f / 128.f) - mu * mu;
    float rstd = rsqrtf(var + 1e-5f);
#pragma unroll
    for (int q = 0; q < 16; ++q) {
      int col = c0 + q;
      float h = (x[q] - mu) * rstd * g1[col] + b1[col];
      sP[row * 128 + col] = h;
      char* p = (char*)sH + row * 256 + ((((col >> 3) ^ (row & 7)) << 4) | ((col & 7) << 1));
      *(unsigned short*)p = f2bf(h);
    }
  }
  __syncthreads();

  // GEMM1: sH @ FWT1 -> gelu -> sT3   [32,128]x[128,512]
  for (int nq = 0; nq < 8; ++nq) {
    int nt = w * 8 + nq;
    bf16x8 wf[4];
    for (int kk = 0; kk < 4; ++kk)
      wf[kk] = *(const bf16x8*)(FWT1 + (size_t)(nt * 16 + l15) * 128 + kk * 32 + l16 * 8);
    for (int mt = 0; mt < 2; ++mt) {
      floatx4 acc = {0.f,0.f,0.f,0.f};
      for (int kk = 0; kk < 4; ++kk) {
        int row = mt * 16 + l15;
        int off = (kk * 64 + l16 * 16) ^ ((row & 7) << 4);
        bf16x8 a = *(const bf16x8*)((const char*)sH + row * 256 + off);
        acc = MFMA16(a, wf[kk], acc);
      }
      int col = nt * 16 + l15;
      float bb = fb1[col];
      for (int r = 0; r < 4; ++r) {
        int row = mt * 16 + l16 * 4 + r;
        char* p = (char*)sT3 + row * 1024 + ((((col >> 3) ^ (row & 7)) << 4) | ((col & 7) << 1));
        *(unsigned short*)p = f2bf(gelu_f(acc[r] + bb));
      }
    }
  }
  __syncthreads();

  // GEMM2: sT3 @ FWT2 + fb2 + h -> sP   [32,512]x[512,128]
  for (int n = 0; n < 2; ++n) {
    int nt = 2 * w + n;
    for (int mt = 0; mt < 2; ++mt) {
      floatx4 acc = {0.f,0.f,0.f,0.f};
      for (int kk = 0; kk < 16; ++kk) {
        int row = mt * 16 + l15;
        int off = (kk * 64 + l16 * 16) ^ ((row & 7) << 4);
        bf16x8 a = *(const bf16x8*)((const char*)sT3 + row * 1024 + off);
        bf16x8 b = *(const bf16x8*)(FWT2 + (size_t)(nt * 16 + l15) * 512 + kk * 32 + l16 * 8);
        acc = MFMA16(a, b, acc);
      }
      int col = nt * 16 + l15;
      float bb = fb2[col];
      for (int r = 0; r < 4; ++r) {
        int row = mt * 16 + l16 * 4 + r;
        sP[row * 128 + col] += acc[r] + bb;
      }
    }
  }
  __syncthreads();

  // LN2 + store (fp32)
  {
    int row = tid >> 3;
    int c0 = (tid & 7) * 16;
    float x[16]; float sum = 0.f, sum2 = 0.f;
#pragma unroll
    for (int q = 0; q < 16; ++q) {
      float xv = sP[row * 128 + c0 + q];
      x[q] = xv; sum += xv; sum2 += xv * xv;
    }
    sum  += __shfl_xor(sum, 1);  sum  += __shfl_xor(sum, 2);  sum  += __shfl_xor(sum, 4);
    sum2 += __shfl_xor(sum2, 1); sum2 += __shfl_xor(sum2, 2); sum2 += __shfl_xor(sum2, 4);
    float mu = sum * (1.f / 128.f);
    float var = sum2 * (1.f / 128.f) - mu * mu;
    float rstd = rsqrtf(var + 1e-5f);
#pragma unroll
    for (int q = 0; q < 16; ++q) {
      int col = c0 + q;
      out[(size_t)(r0 + row) * 128 + col] = (x[q] - mu) * rstd * g2[col] + b2[col];
    }
  }
}

// ---------------------------------------------------------------------------
extern "C" void kernel_launch(void* const* d_in, const int* in_sizes, int n_in,
                              void* d_out, int out_size, void* d_ws, size_t ws_size,
                              hipStream_t stream) {
  const float* node_h  = (const float*)d_in[0];
  const float* edge_h  = (const float*)d_in[1];
  const int*   edge_idx= (const int*)d_in[2];
  const float* seq_emb = (const float*)d_in[3];
  const float* ar_mask = (const float*)d_in[4];
  const float* mW1 = (const float*)d_in[5];
  const float* mb1 = (const float*)d_in[6];
  const float* mW2 = (const float*)d_in[7];
  const float* mb2 = (const float*)d_in[8];
  const float* mW3 = (const float*)d_in[9];
  const float* mb3 = (const float*)d_in[10];
  const float* fW1 = (const float*)d_in[11];
  const float* fb1 = (const float*)d_in[12];
  const float* fW2 = (const float*)d_in[13];
  const float* fb2 = (const float*)d_in[14];
  const float* g1  = (const float*)d_in[15];
  const float* b1  = (const float*)d_in[16];
  const float* g2  = (const float*)d_in[17];
  const float* b2  = (const float*)d_in[18];

  char* ws = (char*)d_ws;
  unsigned short* MT1  = (unsigned short*)(ws + 0);        // [128][512] bf16
  unsigned short* WT2  = (unsigned short*)(ws + 131072);   // [128][128] bf16
  unsigned short* WT3  = (unsigned short*)(ws + 163840);   // [128][128] bf16
  unsigned short* FWT1 = (unsigned short*)(ws + 196608);   // [512][128] bf16
  unsigned short* FWT2 = (unsigned short*)(ws + 327680);   // [128][512] bf16
  float*          Apr  = (float*)(ws + 458752);            // [8192][128] f32
  unsigned short* BS   = (unsigned short*)(ws + 4653056);  // [8192][256] bf16
  float*          sumT2= (float*)(ws + 8847360);           // [8192][128] f32

  hipLaunchKernelGGL(k0_transpose, dim3(224), dim3(256), 0, stream,
                     mW1, mW2, mW3, fW1, fW2, MT1, WT2, WT3, FWT1, FWT2);
  hipLaunchKernelGGL(k1_nodepre, dim3(256), dim3(256), 0, stream,
                     node_h, seq_emb, MT1, mb1, Apr, BS);
  hipLaunchKernelGGL(k2_edge, dim3(2048), dim3(256), 0, stream,
                     edge_h, edge_idx, ar_mask, MT1, WT2, mb2, Apr, BS, sumT2);
  hipLaunchKernelGGL(k3_ff, dim3(256), dim3(256), 0, stream,
                     node_h, sumT2, WT3, mb3, FWT1, FWT2, fb1, fb2,
                     g1, b1, g2, b2, (float*)d_out);
}

// Round 12
// 322.033 us; speedup vs baseline: 1.8069x; 1.8069x over previous
//
#include <hip/hip_runtime.h>

#define KNB 48

typedef float  floatx4 __attribute__((ext_vector_type(4)));
typedef __bf16 bf16x8  __attribute__((ext_vector_type(8)));
typedef unsigned short ushort8  __attribute__((ext_vector_type(8)));
typedef unsigned short ushort4v __attribute__((ext_vector_type(4)));

__device__ __forceinline__ float bf2f(unsigned short b) {
  union { unsigned int u; float f; } v; v.u = ((unsigned int)b) << 16; return v.f;
}
__device__ __forceinline__ unsigned short f2bf(float f) {
  __bf16 h = (__bf16)f;
  union { __bf16 h; unsigned short u; } v; v.h = h; return v.u;
}
__device__ __forceinline__ bf16x8 pack8(floatx4 a, floatx4 b) {
  bf16x8 r;
  r[0] = (__bf16)a[0]; r[1] = (__bf16)a[1]; r[2] = (__bf16)a[2]; r[3] = (__bf16)a[3];
  r[4] = (__bf16)b[0]; r[5] = (__bf16)b[1]; r[6] = (__bf16)b[2]; r[7] = (__bf16)b[3];
  return r;
}
// GELU via sigmoid-form tanh approximation (max |err| ~3e-4 vs exact).
__device__ __forceinline__ float gelu_f(float x) {
  float u = x * (0.7978845608f + 0.0356774081f * x * x);
  float t = __builtin_amdgcn_exp2f(u * -2.8853900818f);
  return x * __builtin_amdgcn_rcpf(1.0f + t);
}

#define MFMA16(a, b, c) __builtin_amdgcn_mfma_f32_16x16x32_bf16((a), (b), (c), 0, 0, 0)

// ---------------------------------------------------------------------------
// k0: transpose fp32 weights into bf16 [n][k] tables
// ---------------------------------------------------------------------------
__global__ __launch_bounds__(256) void k0_transpose(
    const float* mW1, const float* mW2, const float* mW3,
    const float* fW1, const float* fW2,
    unsigned short* MT1, unsigned short* WT2, unsigned short* WT3,
    unsigned short* FWT1, unsigned short* FWT2) {
  __shared__ unsigned short tile[32][33];
  int b = blockIdx.x;
  const float* src; unsigned short* dst; int Kd, Nd, t;
  if (b < 64)       { src = mW1; dst = MT1;  Kd = 512; Nd = 128; t = b; }
  else if (b < 80)  { src = mW2; dst = WT2;  Kd = 128; Nd = 128; t = b - 64; }
  else if (b < 96)  { src = mW3; dst = WT3;  Kd = 128; Nd = 128; t = b - 80; }
  else if (b < 160) { src = fW1; dst = FWT1; Kd = 128; Nd = 512; t = b - 96; }
  else              { src = fW2; dst = FWT2; Kd = 512; Nd = 128; t = b - 160; }
  int tN = Nd >> 5;
  int tk = t / tN, tn = t % tN;
  int tx = threadIdx.x & 31, ty = threadIdx.x >> 5;  // 32x8
  for (int r = 0; r < 4; ++r) {
    int row = ty + r * 8;
    tile[row][tx] = f2bf(src[(size_t)(tk * 32 + row) * Nd + tn * 32 + tx]);
  }
  __syncthreads();
  for (int r = 0; r < 4; ++r) {
    int row = ty + r * 8;
    dst[(size_t)(tn * 32 + row) * Kd + tk * 32 + tx] = tile[tx][row];
  }
}

// ---------------------------------------------------------------------------
// k1: node precompute tables:
//   Apr[i] = node_h[i] @ mW1[0:128]   + mb1          (fp32)
//   BS[j][0:128]   = node_h[j] @ mW1[128:256]        (bf16)
//   BS[j][128:256] = seq_emb[j] @ mW1[384:512]       (bf16)
// ---------------------------------------------------------------------------
__global__ __launch_bounds__(256) void k1_nodepre(
    const float* node_h, const float* seq_emb,
    const unsigned short* MT1, const float* mb1,
    float* Apr, unsigned short* BS) {
  __shared__ __align__(16) unsigned short sX[2][32 * 128];
  int r0 = blockIdx.x * 32;
  int tid = threadIdx.x, lane = tid & 63, w = tid >> 6;
  int l15 = lane & 15, l16 = lane >> 4;

  for (int mset = 0; mset < 2; ++mset) {
    const float* src = mset ? (seq_emb + (size_t)r0 * 128) : (node_h + (size_t)r0 * 128);
    for (int k = 0; k < 4; ++k) {
      int f = tid + 256 * k;
      floatx4 v = ((const floatx4*)src)[f];
      int row = f >> 5, hc = f & 31, c = hc >> 1, half = hc & 1;
      ushort4v o;
      o[0] = f2bf(v[0]); o[1] = f2bf(v[1]); o[2] = f2bf(v[2]); o[3] = f2bf(v[3]);
      *(ushort4v*)((char*)&sX[mset][0] + row * 256 + ((c ^ (row & 7)) << 4) + half * 8) = o;
    }
  }
  __syncthreads();

  for (int q = 0; q < 6; ++q) {
    int job = w + 4 * q;
    int kind = job >> 3;                 // 0:Apr 1:B 2:S
    int nt = job & 7;
    int colOff = (kind == 0) ? 0 : (kind == 1) ? 128 : 384;
    const unsigned short* X = sX[kind == 2 ? 1 : 0];
    bf16x8 wf[4];
    for (int kk = 0; kk < 4; ++kk)
      wf[kk] = *(const bf16x8*)(MT1 + (size_t)(nt * 16 + l15) * 512 + colOff + kk * 32 + l16 * 8);
    for (int mt = 0; mt < 2; ++mt) {
      floatx4 acc = {0.f, 0.f, 0.f, 0.f};
      for (int kk = 0; kk < 4; ++kk) {
        int row = mt * 16 + l15;
        int off = (kk * 64 + l16 * 16) ^ ((row & 7) << 4);
        bf16x8 a = *(const bf16x8*)((const char*)X + row * 256 + off);
        acc = MFMA16(a, wf[kk], acc);
      }
      int col = nt * 16 + l15;
      for (int r = 0; r < 4; ++r) {
        int row = r0 + mt * 16 + l16 * 4 + r;
        if (kind == 0)      Apr[(size_t)row * 128 + col] = acc[r] + mb1[col];
        else if (kind == 1) BS[(size_t)row * 256 + col] = f2bf(acc[r]);
        else                BS[(size_t)row * 256 + 128 + col] = f2bf(acc[r]);
      }
    }
  }
}

// ---------------------------------------------------------------------------
// k2: edge MLP, transposed orientation (edges on MFMA N axis), SPLIT over
// 2 waves per node to kill the R9/R11 register spill:
//   block = 128 thr = 2 waves = 1 node; wave w owns features w*64..w*64+63
//   (4 mt-tiles) -> vsum[16], bE[4], bT[4] ~= 80 live VGPR, no cap.
//   t1 shared via 8 KB double-buffered LDS; 1 barrier per 16-edge subtile.
//   A-frag = weight tables; B-frag = E^T direct from global (no staging);
//   C-in L1 = gvec^T (no gvec pass); L3 folded into k3 (sum_e t2 @ W3).
// Math mapping identical to R11 (passed, absmax 0.03125).
// ---------------------------------------------------------------------------
__global__ __launch_bounds__(128) void k2_edge(
    const float* edge_h, const int* edge_idx, const float* ar_mask,
    const unsigned short* MT1, const unsigned short* WT2,
    const float* mb2,
    const float* Apr, const unsigned short* BS,
    float* sumT2) {
  __shared__ __align__(16) unsigned short X[2][16 * 128];   // t1, double-buffered
  int tid = threadIdx.x, lane = tid & 63, w = tid >> 6;     // w in {0,1}
  int l15 = lane & 15, l16 = lane >> 4;
  int node = blockIdx.x;
  int mtbase = w * 4;                      // wave's feature tiles
  int xsw = (l15 & 7) << 4;

  float vsum[16];
#pragma unroll
  for (int q = 0; q < 16; ++q) vsum[q] = 0.f;

  for (int sub = 0; sub < 3; ++sub) {
    char* Xb = (char*)&X[sub & 1][0];
    int e = node * KNB + sub * 16 + l15;
    int jj = edge_idx[e];
    float mk = ar_mask[e];

    // E^T B-frags direct from global fp32 (lane l15 = edge, l16 = k-chunk)
    bf16x8 bE[4];
#pragma unroll
    for (int kk = 0; kk < 4; ++kk) {
      const floatx4* ep = (const floatx4*)(edge_h + (size_t)e * 128 + kk * 32 + l16 * 8);
      bE[kk] = pack8(ep[0], ep[1]);
    }

    // ---- layer 1 (this wave's 4 mt): C-in = gvec^T; += W1e x E^T; gelu -> Xb
#pragma unroll
    for (int m = 0; m < 4; ++m) {
      int mt = mtbase + m;
      int f0 = mt * 16 + l16 * 4;
      floatx4 ap = *(const floatx4*)(Apr + (size_t)node * 128 + f0);
      ushort4v vb = *(const ushort4v*)(BS + (size_t)jj * 256 + f0);
      ushort4v vs = *(const ushort4v*)(BS + (size_t)jj * 256 + 128 + f0);
      floatx4 c;
#pragma unroll
      for (int r = 0; r < 4; ++r) c[r] = ap[r] + bf2f(vb[r]) + mk * bf2f(vs[r]);
#pragma unroll
      for (int kk = 0; kk < 4; ++kk) {
        bf16x8 a = *(const bf16x8*)(MT1 + (size_t)(mt * 16 + l15) * 512 + 256 + kk * 32 + l16 * 8);
        c = MFMA16(a, bE[kk], c);
      }
      ushort4v o;
#pragma unroll
      for (int r = 0; r < 4; ++r) o[r] = f2bf(gelu_f(c[r]));
      *(ushort4v*)(Xb + l15 * 256 + ((mt * 32 + l16 * 8) ^ xsw)) = o;
    }
    __syncthreads();   // t1 halves complete; safe: next sub writes other buffer

    // ---- layer 2: full-K t1 B-frags from Xb; C-in = mb2; gelu -> vsum (fp32)
    bf16x8 bT[4];
#pragma unroll
    for (int kk = 0; kk < 4; ++kk)
      bT[kk] = *(const bf16x8*)(Xb + l15 * 256 + ((kk * 64 + l16 * 16) ^ xsw));
#pragma unroll
    for (int m = 0; m < 4; ++m) {
      int mt = mtbase + m;
      int f0 = mt * 16 + l16 * 4;
      floatx4 c = *(const floatx4*)(mb2 + f0);
#pragma unroll
      for (int kk = 0; kk < 4; ++kk) {
        bf16x8 a = *(const bf16x8*)(WT2 + (size_t)(mt * 16 + l15) * 128 + kk * 32 + l16 * 8);
        c = MFMA16(a, bT[kk], c);
      }
#pragma unroll
      for (int r = 0; r < 4; ++r) vsum[m * 4 + r] += gelu_f(c[r]);
    }
  }

  // ---- reduce over the 16 edge-lanes and write sum_t2[node] (fp32)
#pragma unroll
  for (int q = 0; q < 16; ++q) {
    vsum[q] += __shfl_xor(vsum[q], 1);
    vsum[q] += __shfl_xor(vsum[q], 2);
    vsum[q] += __shfl_xor(vsum[q], 4);
    vsum[q] += __shfl_xor(vsum[q], 8);
  }
  if (l15 == 0) {
#pragma unroll
    for (int m = 0; m < 4; ++m) {
      int f0 = (mtbase + m) * 16 + l16 * 4;
      floatx4 o;
#pragma unroll
      for (int r = 0; r < 4; ++r) o[r] = vsum[m * 4 + r];
      *(floatx4*)(sumT2 + (size_t)node * 128 + f0) = o;
    }
  }
}

// ---------------------------------------------------------------------------
// k3: agg = sumT2 @ W3 + 48*mb3 (tiny GEMV via MFMA), then
//     h=LN(node_h+agg); ff=gelu(h@fW1+fb1)@fW2+fb2; out=LN(h+ff)
// ---------------------------------------------------------------------------
__global__ __launch_bounds__(256) void k3_ff(
    const float* node_h, const float* sumT2,
    const unsigned short* WT3, const float* mb3,
    const unsigned short* FWT1, const unsigned short* FWT2,
    const float* fb1, const float* fb2,
    const float* g1, const float* b1,
    const float* g2, const float* b2,
    float* out) {
  __shared__ __align__(16) unsigned short sS[32 * 128];
  __shared__ float sAgg[32 * 128];
  __shared__ __align__(16) unsigned short sH[32 * 128];
  __shared__ __align__(16) unsigned short sT3[32 * 512];
  __shared__ float sP[32 * 128];
  int r0 = blockIdx.x * 32;
  int tid = threadIdx.x, lane = tid & 63, w = tid >> 6;
  int l15 = lane & 15, l16 = lane >> 4;

  // stage sumT2 -> sS (bf16, swizzled)
  {
    const float* src = sumT2 + (size_t)r0 * 128;
    for (int k = 0; k < 4; ++k) {
      int f = tid + 256 * k;
      floatx4 v = ((const floatx4*)src)[f];
      int row = f >> 5, hc = f & 31, c = hc >> 1, half = hc & 1;
      ushort4v o;
      o[0] = f2bf(v[0]); o[1] = f2bf(v[1]); o[2] = f2bf(v[2]); o[3] = f2bf(v[3]);
      *(ushort4v*)((char*)sS + row * 256 + ((c ^ (row & 7)) << 4) + half * 8) = o;
    }
  }
  __syncthreads();

  // GEMV: sAgg = sS @ WT3 + 48*mb3
  for (int n = 0; n < 2; ++n) {
    int nt = w * 2 + n;
    bf16x8 wf[4];
    for (int kk = 0; kk < 4; ++kk)
      wf[kk] = *(const bf16x8*)(WT3 + (size_t)(nt * 16 + l15) * 128 + kk * 32 + l16 * 8);
    for (int mt = 0; mt < 2; ++mt) {
      floatx4 acc = {0.f,0.f,0.f,0.f};
      for (int kk = 0; kk < 4; ++kk) {
        int row = mt * 16 + l15;
        int off = (kk * 64 + l16 * 16) ^ ((row & 7) << 4);
        bf16x8 a = *(const bf16x8*)((const char*)sS + row * 256 + off);
        acc = MFMA16(a, wf[kk], acc);
      }
      int col = nt * 16 + l15;
      for (int r = 0; r < 4; ++r) {
        int row = mt * 16 + l16 * 4 + r;
        sAgg[row * 128 + col] = acc[r] + 48.0f * mb3[col];
      }
    }
  }
  __syncthreads();

  // load + LN1 (node_h global + sAgg LDS)
  {
    int row = tid >> 3;
    int c0 = (tid & 7) * 16;
    const floatx4* nh4 = (const floatx4*)(node_h + (size_t)(r0 + row) * 128 + c0);
    const floatx4* ag4 = (const floatx4*)(&sAgg[row * 128 + c0]);
    float x[16]; float sum = 0.f, sum2 = 0.f;
#pragma unroll
    for (int q4 = 0; q4 < 4; ++q4) {
      floatx4 a = nh4[q4], g = ag4[q4];
#pragma unroll
      for (int j = 0; j < 4; ++j) {
        float xv = a[j] + g[j];
        x[q4 * 4 + j] = xv; sum += xv; sum2 += xv * xv;
      }
    }
    sum  += __shfl_xor(sum, 1);  sum  += __shfl_xor(sum, 2);  sum  += __shfl_xor(sum, 4);
    sum2 += __shfl_xor(sum2, 1); sum2 += __shfl_xor(sum2, 2); sum2 += __shfl_xor(sum2, 4);
    float mu = sum * (1.f / 128.f);
    float var = sum2 * (1.f / 128.f) - mu * mu;
    float rstd = rsqrtf(var + 1e-5f);
#pragma unroll
    for (int q = 0; q < 16; ++q) {
      int col = c0 + q;
      float h = (x[q] - mu) * rstd * g1[col] + b1[col];
      sP[row * 128 + col] = h;
      char* p = (char*)sH + row * 256 + ((((col >> 3) ^ (row & 7)) << 4) | ((col & 7) << 1));
      *(unsigned short*)p = f2bf(h);
    }
  }
  __syncthreads();

  // GEMM1: sH @ FWT1 -> gelu -> sT3   [32,128]x[128,512]
  for (int nq = 0; nq < 8; ++nq) {
    int nt = w * 8 + nq;
    bf16x8 wf[4];
    for (int kk = 0; kk < 4; ++kk)
      wf[kk] = *(const bf16x8*)(FWT1 + (size_t)(nt * 16 + l15) * 128 + kk * 32 + l16 * 8);
    for (int mt = 0; mt < 2; ++mt) {
      floatx4 acc = {0.f,0.f,0.f,0.f};
      for (int kk = 0; kk < 4; ++kk) {
        int row = mt * 16 + l15;
        int off = (kk * 64 + l16 * 16) ^ ((row & 7) << 4);
        bf16x8 a = *(const bf16x8*)((const char*)sH + row * 256 + off);
        acc = MFMA16(a, wf[kk], acc);
      }
      int col = nt * 16 + l15;
      float bb = fb1[col];
      for (int r = 0; r < 4; ++r) {
        int row = mt * 16 + l16 * 4 + r;
        char* p = (char*)sT3 + row * 1024 + ((((col >> 3) ^ (row & 7)) << 4) | ((col & 7) << 1));
        *(unsigned short*)p = f2bf(gelu_f(acc[r] + bb));
      }
    }
  }
  __syncthreads();

  // GEMM2: sT3 @ FWT2 + fb2 + h -> sP   [32,512]x[512,128]
  for (int n = 0; n < 2; ++n) {
    int nt = 2 * w + n;
    for (int mt = 0; mt < 2; ++mt) {
      floatx4 acc = {0.f,0.f,0.f,0.f};
      for (int kk = 0; kk < 16; ++kk) {
        int row = mt * 16 + l15;
        int off = (kk * 64 + l16 * 16) ^ ((row & 7) << 4);
        bf16x8 a = *(const bf16x8*)((const char*)sT3 + row * 1024 + off);
        bf16x8 b = *(const bf16x8*)(FWT2 + (size_t)(nt * 16 + l15) * 512 + kk * 32 + l16 * 8);
        acc = MFMA16(a, b, acc);
      }
      int col = nt * 16 + l15;
      float bb = fb2[col];
      for (int r = 0; r < 4; ++r) {
        int row = mt * 16 + l16 * 4 + r;
        sP[row * 128 + col] += acc[r] + bb;
      }
    }
  }
  __syncthreads();

  // LN2 + store (fp32)
  {
    int row = tid >> 3;
    int c0 = (tid & 7) * 16;
    float x[16]; float sum = 0.f, sum2 = 0.f;
#pragma unroll
    for (int q = 0; q < 16; ++q) {
      float xv = sP[row * 128 + c0 + q];
      x[q] = xv; sum += xv; sum2 += xv * xv;
    }
    sum  += __shfl_xor(sum, 1);  sum  += __shfl_xor(sum, 2);  sum  += __shfl_xor(sum, 4);
    sum2 += __shfl_xor(sum2, 1); sum2 += __shfl_xor(sum2, 2); sum2 += __shfl_xor(sum2, 4);
    float mu = sum * (1.f / 128.f);
    float var = sum2 * (1.f / 128.f) - mu * mu;
    float rstd = rsqrtf(var + 1e-5f);
#pragma unroll
    for (int q = 0; q < 16; ++q) {
      int col = c0 + q;
      out[(size_t)(r0 + row) * 128 + col] = (x[q] - mu) * rstd * g2[col] + b2[col];
    }
  }
}

// ---------------------------------------------------------------------------
extern "C" void kernel_launch(void* const* d_in, const int* in_sizes, int n_in,
                              void* d_out, int out_size, void* d_ws, size_t ws_size,
                              hipStream_t stream) {
  const float* node_h  = (const float*)d_in[0];
  const float* edge_h  = (const float*)d_in[1];
  const int*   edge_idx= (const int*)d_in[2];
  const float* seq_emb = (const float*)d_in[3];
  const float* ar_mask = (const float*)d_in[4];
  const float* mW1 = (const float*)d_in[5];
  const float* mb1 = (const float*)d_in[6];
  const float* mW2 = (const float*)d_in[7];
  const float* mb2 = (const float*)d_in[8];
  const float* mW3 = (const float*)d_in[9];
  const float* mb3 = (const float*)d_in[10];
  const float* fW1 = (const float*)d_in[11];
  const float* fb1 = (const float*)d_in[12];
  const float* fW2 = (const float*)d_in[13];
  const float* fb2 = (const float*)d_in[14];
  const float* g1  = (const float*)d_in[15];
  const float* b1  = (const float*)d_in[16];
  const float* g2  = (const float*)d_in[17];
  const float* b2  = (const float*)d_in[18];

  char* ws = (char*)d_ws;
  unsigned short* MT1  = (unsigned short*)(ws + 0);        // [128][512] bf16
  unsigned short* WT2  = (unsigned short*)(ws + 131072);   // [128][128] bf16
  unsigned short* WT3  = (unsigned short*)(ws + 163840);   // [128][128] bf16
  unsigned short* FWT1 = (unsigned short*)(ws + 196608);   // [512][128] bf16
  unsigned short* FWT2 = (unsigned short*)(ws + 327680);   // [128][512] bf16
  float*          Apr  = (float*)(ws + 458752);            // [8192][128] f32
  unsigned short* BS   = (unsigned short*)(ws + 4653056);  // [8192][256] bf16
  float*          sumT2= (float*)(ws + 8847360);           // [8192][128] f32

  hipLaunchKernelGGL(k0_transpose, dim3(224), dim3(256), 0, stream,
                     mW1, mW2, mW3, fW1, fW2, MT1, WT2, WT3, FWT1, FWT2);
  hipLaunchKernelGGL(k1_nodepre, dim3(256), dim3(256), 0, stream,
                     node_h, seq_emb, MT1, mb1, Apr, BS);
  hipLaunchKernelGGL(k2_edge, dim3(8192), dim3(128), 0, stream,
                     edge_h, edge_idx, ar_mask, MT1, WT2, mb2, Apr, BS, sumT2);
  hipLaunchKernelGGL(k3_ff, dim3(256), dim3(256), 0, stream,
                     node_h, sumT2, WT3, mb3, FWT1, FWT2, fb1, fb2,
                     g1, b1, g2, b2, (float*)d_out);
}